// Round 10
// baseline (85.985 us; speedup 1.0000x reference)
//
#include <hip/hip_runtime.h>

// Trilinear interpolation over a 256^3 f32 grid. Round 10:
//  - 1024 anisotropic bins (16x32x32 cells); 74KB LDS halo region, 2 interp
//    blocks/CU (rounds 8-9)
//  - capacity-padded buckets, no hist/scan (round 8)
//  - NEW: 16-way SPLIT CURSORS: bin cap region pre-partitioned into 16
//    sub-regions; block reserves from sub-cursor (blockIdx&15, bin). Same-
//    address atomic chain drops 489 -> ~31 (was the 40us scatter critical
//    path). Interp walks the 16 ragged sub-segments via LDS prefix.
//  - NEW: payload packed as aligned float4 (no 12B straddling stores).

#define NBINS 1024            // 16 x 8 x 8 bins (x:16 cells, y:32, z:32)
#define NSUB 16               // cursor split ways
#define SPTS 4096             // points per scatter block
#define SPPT 8                // points per thread (512-thread blocks)

#define RX 17                 // region x extent (16 + halo)
#define RYZ 1089              // 33*33
#define RN (RX * RYZ)         // 18513 floats = 74052 B

#define ITHREADS 1024         // interp block size (16 waves); 2 blocks/CU
#define CSTRIDE 16            // cursor line-padding stride (u32 units)

__device__ __forceinline__ float interp_one(float ix, float iy, float iz,
                                            const float* __restrict__ g,
                                            bool& valid) {
    valid = (ix >= 0.0f) && (ix <= 255.0f) &&
            (iy >= 0.0f) && (iy <= 255.0f) &&
            (iz >= 0.0f) && (iz <= 255.0f);
    if (!valid) return 0.0f;

    float flx = floorf(ix), fcx = ceilf(ix);
    float fly = floorf(iy), fcy = ceilf(iy);
    float flz = floorf(iz), fcz = ceilf(iz);

    int x0 = (int)flx, x1 = (int)fcx;
    int y0 = (int)fly, y1 = (int)fcy;
    int z0 = (int)flz, z1 = (int)fcz;

    float wsx = ix - flx; if (wsx == 0.0f) wsx = 1.0f;
    float wux = fcx - ix; if (wux == 0.0f) wux = 1.0f;
    float wsy = iy - fly; if (wsy == 0.0f) wsy = 1.0f;
    float wuy = fcy - iy; if (wuy == 0.0f) wuy = 1.0f;
    float wsz = iz - flz; if (wsz == 0.0f) wsz = 1.0f;
    float wuz = fcz - iz; if (wuz == 0.0f) wuz = 1.0f;

    int bx0 = x0 << 16, bx1 = x1 << 16;
    int by0 = y0 << 8,  by1 = y1 << 8;

    float v0 = g[bx0 + by0 + z0];  float w0 = wux * wuy * wuz;
    float v1 = g[bx1 + by0 + z0];  float w1 = wsx * wuy * wuz;
    float v2 = g[bx0 + by1 + z0];  float w2 = wux * wsy * wuz;
    float v3 = g[bx1 + by1 + z0];  float w3 = wsx * wsy * wuz;
    float v4 = g[bx0 + by0 + z1];  float w4 = wux * wuy * wsz;
    float v5 = g[bx1 + by0 + z1];  float w5 = wsx * wuy * wsz;
    float v6 = g[bx0 + by1 + z1];  float w6 = wux * wsy * wsz;
    float v7 = g[bx1 + by1 + z1];  float w7 = wsx * wsy * wsz;

    float num = v0 * w0 + v1 * w1 + v2 * w2 + v3 * w3 +
                v4 * w4 + v5 * w5 + v6 * w6 + v7 * w7;
    float den = w0 + w1 + w2 + w3 + w4 + w5 + w6 + w7;
    return num / den;
}

// bins: x -> 16 cells (4-bit), y -> 32 cells (3-bit), z -> 32 cells (3-bit)
__device__ __forceinline__ unsigned bin_key(float ix, float iy, float iz) {
    ix = fminf(fmaxf(ix, 0.0f), 255.0f);
    iy = fminf(fmaxf(iy, 0.0f), 255.0f);
    iz = fminf(fmaxf(iz, 0.0f), 255.0f);
    int bx = ((int)ix) >> 4;
    int by = ((int)iy) >> 5;
    int bz = ((int)iz) >> 5;
    return (unsigned)((bx << 6) | (by << 3) | bz);   // 1024 bins
}

// ---------- fallback (round-1) kernel ----------
__global__ __launch_bounds__(256) void simplegrid_direct(
    const float* __restrict__ x, const float* __restrict__ grid,
    const float* __restrict__ lower, const float* __restrict__ res,
    float* __restrict__ out, int n)
{
    int i = blockIdx.x * blockDim.x + threadIdx.x;
    if (i >= n) return;
    float ix = (x[3 * i + 0] - lower[0]) / res[0];
    float iy = (x[3 * i + 1] - lower[1]) / res[1];
    float iz = (x[3 * i + 2] - lower[2]) / res[2];
    bool valid;
    float v = interp_one(ix, iy, iz, grid, valid);
    out[i] = valid ? v : 0.0f;
}

// ---------- bucketed pipeline ----------
// cursor[(s<<10)|b] (line-padded) seeded to b*cap + s*(cap/NSUB)
__global__ __launch_bounds__(512) void init_cursor_kernel(
    unsigned* __restrict__ cursor, unsigned cap)
{
    int t = blockIdx.x * 512 + threadIdx.x;     // grid = 32 blocks
    if (t < NBINS * NSUB) {
        unsigned s = (unsigned)t >> 10;
        unsigned b = (unsigned)t & (NBINS - 1);
        cursor[(size_t)t * CSTRIDE] = b * cap + s * (cap / NSUB);
    }
}

__global__ __launch_bounds__(512) void scatter_kernel(
    const float* __restrict__ x, const float* __restrict__ lower,
    const float* __restrict__ res, unsigned* __restrict__ cursor,
    float4* __restrict__ p4, unsigned* __restrict__ posbuf, int n)
{
    __shared__ float sxl[SPTS], syl[SPTS], szl[SPTS];       // 48 KB
    __shared__ unsigned short kyl[SPTS];                    // 8 KB
    __shared__ unsigned cnt[NBINS], pfx[NBINS], lcur[NBINS], gbase[NBINS]; // 16 KB
    __shared__ unsigned wsum[8];

    int t = threadIdx.x;
    int lane = t & 63, wave = t >> 6;
    cnt[2 * t] = 0u; cnt[2 * t + 1] = 0u;
    __syncthreads();

    float l0 = lower[0], l1 = lower[1], l2 = lower[2];
    float r0 = res[0],   r1 = res[1],   r2 = res[2];
    int base = blockIdx.x * SPTS;

    float px[SPPT], py[SPPT], pz[SPPT];
    unsigned key[SPPT];
    #pragma unroll
    for (int k = 0; k < SPPT; ++k) {
        int p = base + k * 512 + t;
        if (p < n) {
            px[k] = (x[3 * p + 0] - l0) / r0;
            py[k] = (x[3 * p + 1] - l1) / r1;
            pz[k] = (x[3 * p + 2] - l2) / r2;
            key[k] = bin_key(px[k], py[k], pz[k]);
            atomicAdd(&cnt[key[k]], 1u);
        }
    }
    __syncthreads();

    // global reservation on this block's sub-cursor (chain ~489/16 ~= 31),
    // rotated per block, issued before the scan so latency overlaps it
    unsigned sub = (unsigned)blockIdx.x & (NSUB - 1);
    unsigned h = ((unsigned)blockIdx.x * 131u) & (NBINS - 1);
    unsigned b0 = (2u * t + h) & (NBINS - 1);
    unsigned b1 = (2u * t + 1u + h) & (NBINS - 1);
    unsigned cb0 = cnt[b0], cb1 = cnt[b1];
    if (cb0) gbase[b0] = atomicAdd(&cursor[(size_t)((sub << 10) | b0) * CSTRIDE], cb0);
    if (cb1) gbase[b1] = atomicAdd(&cursor[(size_t)((sub << 10) | b1) * CSTRIDE], cb1);

    // exclusive prefix over 1024 bins: 2 bins per thread, wave scan + wsum
    unsigned c0 = cnt[2 * t], c1 = cnt[2 * t + 1];
    unsigned v = c0 + c1;
    unsigned s = v;
    #pragma unroll
    for (int off = 1; off < 64; off <<= 1) {
        unsigned u = __shfl_up(s, off);
        if (lane >= off) s += u;
    }
    if (lane == 63) wsum[wave] = s;
    __syncthreads();
    unsigned woff = 0, tot = 0;
    #pragma unroll
    for (int w = 0; w < 8; ++w) { if (w < wave) woff += wsum[w]; tot += wsum[w]; }
    unsigned excl = woff + s - v;
    pfx[2 * t] = excl;          lcur[2 * t] = excl;
    pfx[2 * t + 1] = excl + c0; lcur[2 * t + 1] = excl + c0;
    __syncthreads();

    // placement into LDS (bin-sorted) + pos written directly (coalesced addr)
    #pragma unroll
    for (int k = 0; k < SPPT; ++k) {
        int p = base + k * 512 + t;
        if (p < n) {
            unsigned lp = atomicAdd(&lcur[key[k]], 1u);
            sxl[lp] = px[k]; syl[lp] = py[k]; szl[lp] = pz[k];
            kyl[lp] = (unsigned short)key[k];
            posbuf[p] = gbase[key[k]] + (lp - pfx[key[k]]);
        }
    }
    __syncthreads();

    // flush in sorted order -> contiguous 16B/pt runs
    for (unsigned q = t; q < tot; q += 512) {
        unsigned kk = kyl[q];
        unsigned dst = gbase[kk] + (q - pfx[kk]);
        p4[dst] = make_float4(sxl[q], syl[q], szl[q], 0.0f);
    }
}

// One block per bin: stage 17x33x33 halo region (74KB) into LDS, gather from
// LDS. Bin's points live in 16 ragged sub-segments (split cursors).
__global__ __launch_bounds__(ITHREADS) void interp_lds_kernel(
    const float4* __restrict__ p4, const float* __restrict__ grid,
    const unsigned* __restrict__ cursor, float* __restrict__ osort,
    unsigned cap)
{
    extern __shared__ float lds[];
    __shared__ unsigned sstart[NSUB + 1];   // prefix over sub-segment counts
    __shared__ unsigned sbase[NSUB];        // absolute start of each sub-seg

    int b = blockIdx.x;
    int t = threadIdx.x;
    int bx0 = (b >> 6) << 4;          // x base (16-cell bins)
    int by0 = ((b >> 3) & 7) << 5;    // y base (32-cell bins)
    int bz0 = (b & 7) << 5;           // z base (32-cell bins)

    // sub-segment table (one wave does it while others start staging)
    if (t < NSUB) {
        unsigned subcap = cap / NSUB;
        unsigned st = (unsigned)b * cap + (unsigned)t * subcap;
        unsigned en = cursor[(size_t)(((unsigned)t << 10) | (unsigned)b) * CSTRIDE];
        sbase[t] = st;
        sstart[t] = en - st;          // count, prefixed below
    }

    // stage region: idx = lx*1089 + ly*33 + lz (z rows contiguous)
    for (int i = t; i < RN; i += ITHREADS) {
        int lx = i / RYZ;
        int r  = i - lx * RYZ;
        int ly = r / 33;
        int lz = r - ly * 33;
        int gx = bx0 + lx; if (gx > 255) gx = 255;
        int gy = by0 + ly; if (gy > 255) gy = 255;
        int gz = bz0 + lz; if (gz > 255) gz = 255;
        lds[i] = grid[(gx << 16) + (gy << 8) + gz];
    }
    __syncthreads();

    if (t == 0) {                     // tiny serial prefix over 16 counts
        unsigned acc = 0;
        #pragma unroll
        for (int s2 = 0; s2 < NSUB; ++s2) {
            unsigned c = sstart[s2];
            sstart[s2] = acc;
            acc += c;
        }
        sstart[NSUB] = acc;
    }
    __syncthreads();

    float fbx = (float)bx0, fby = (float)by0, fbz = (float)bz0;
    unsigned tot = sstart[NSUB];

    for (unsigned idx = t; idx < tot; idx += ITHREADS) {
        // binary search: sub-segment s with sstart[s] <= idx < sstart[s+1]
        unsigned lo = 0, hi = NSUB;
        #pragma unroll
        for (int it = 0; it < 4; ++it) {
            unsigned mid = (lo + hi) >> 1;
            if (sstart[mid] <= idx) lo = mid; else hi = mid;
        }
        unsigned j = sbase[lo] + (idx - sstart[lo]);

        float4 p = p4[j];
        float ix = p.x, iy = p.y, iz = p.z;
        bool valid = (ix >= 0.0f) && (ix <= 255.0f) &&
                     (iy >= 0.0f) && (iy <= 255.0f) &&
                     (iz >= 0.0f) && (iz <= 255.0f);
        float fx = fminf(fmaxf(ix, 0.0f), 255.0f) - fbx;
        float fy = fminf(fmaxf(iy, 0.0f), 255.0f) - fby;
        float fz = fminf(fmaxf(iz, 0.0f), 255.0f) - fbz;

        float flx = floorf(fx), fcx = ceilf(fx);
        float fly = floorf(fy), fcy = ceilf(fy);
        float flz = floorf(fz), fcz = ceilf(fz);
        int x0 = (int)flx, x1 = (int)fcx;
        int y0 = (int)fly, y1 = (int)fcy;
        int z0 = (int)flz, z1 = (int)fcz;

        float wsx = fx - flx; if (wsx == 0.0f) wsx = 1.0f;
        float wux = fcx - fx; if (wux == 0.0f) wux = 1.0f;
        float wsy = fy - fly; if (wsy == 0.0f) wsy = 1.0f;
        float wuy = fcy - fy; if (wuy == 0.0f) wuy = 1.0f;
        float wsz = fz - flz; if (wsz == 0.0f) wsz = 1.0f;
        float wuz = fcz - fz; if (wuz == 0.0f) wuz = 1.0f;

        int ax0 = x0 * RYZ, ax1 = x1 * RYZ;
        int ay0 = y0 * 33,  ay1 = y1 * 33;

        float v0 = lds[ax0 + ay0 + z0];  float w0 = wux * wuy * wuz;
        float v1 = lds[ax1 + ay0 + z0];  float w1 = wsx * wuy * wuz;
        float v2 = lds[ax0 + ay1 + z0];  float w2 = wux * wsy * wuz;
        float v3 = lds[ax1 + ay1 + z0];  float w3 = wsx * wsy * wuz;
        float v4 = lds[ax0 + ay0 + z1];  float w4 = wux * wuy * wsz;
        float v5 = lds[ax1 + ay0 + z1];  float w5 = wsx * wuy * wsz;
        float v6 = lds[ax0 + ay1 + z1];  float w6 = wux * wsy * wsz;
        float v7 = lds[ax1 + ay1 + z1];  float w7 = wsx * wsy * wsz;

        float num = v0 * w0 + v1 * w1 + v2 * w2 + v3 * w3 +
                    v4 * w4 + v5 * w5 + v6 * w6 + v7 * w7;
        float den = w0 + w1 + w2 + w3 + w4 + w5 + w6 + w7;
        osort[j] = valid ? (num / den) : 0.0f;
    }
}

__global__ __launch_bounds__(256) void permute_kernel(
    const float* __restrict__ out_sorted, const unsigned* __restrict__ pos,
    float* __restrict__ out, int n)
{
    int i = blockIdx.x * blockDim.x + threadIdx.x;
    if (i < n) out[i] = out_sorted[pos[i]];
}

extern "C" void kernel_launch(void* const* d_in, const int* in_sizes, int n_in,
                              void* d_out, int out_size, void* d_ws, size_t ws_size,
                              hipStream_t stream) {
    const float* x     = (const float*)d_in[0];
    const float* grid  = (const float*)d_in[1];
    const float* lower = (const float*)d_in[2];
    const float* res   = (const float*)d_in[3];
    float* out = (float*)d_out;

    int n = in_sizes[0] / 3;
    int blocks_pt = (n + 255) / 256;

    // ws: cursor (16*1024 line-padded = 1MB) + p4 (16B/slot) + osort (4B/slot)
    //     + posbuf (4B/pt)
    size_t cur_bytes = (size_t)NBINS * NSUB * CSTRIDE * 4;   // 1 MB
    size_t fixed = cur_bytes + (size_t)n * 4;
    unsigned cap = 0;
    if (ws_size > fixed) {
        size_t c = (ws_size - fixed) / ((size_t)NBINS * 20);
        cap = (unsigned)(c > 8192 ? 8192 : c);
        cap &= ~(unsigned)(NSUB - 1);                        // multiple of 16
    }

    bool lds_ok = (hipFuncSetAttribute(
        (const void*)interp_lds_kernel,
        hipFuncAttributeMaxDynamicSharedMemorySize,
        RN * (int)sizeof(float)) == hipSuccess);

    // subcap = cap/16 must be >= 256 (mean fill 122, +12 sigma) -> cap >= 4096
    if (cap < 4096 || !lds_ok) {
        simplegrid_direct<<<blocks_pt, 256, 0, stream>>>(x, grid, lower, res, out, n);
        return;
    }

    char* ws = (char*)d_ws;
    size_t off_p4    = cur_bytes;
    size_t off_osort = off_p4 + (size_t)NBINS * cap * 16;
    size_t off_pos   = off_osort + (size_t)NBINS * cap * 4;

    unsigned* cursor = (unsigned*)ws;
    float4*   p4     = (float4*)(ws + off_p4);
    float*    osort  = (float*)(ws + off_osort);
    unsigned* posbuf = (unsigned*)(ws + off_pos);

    int blocks_sort = (n + SPTS - 1) / SPTS;

    init_cursor_kernel<<<32, 512, 0, stream>>>(cursor, cap);
    scatter_kernel<<<blocks_sort, 512, 0, stream>>>(
        x, lower, res, cursor, p4, posbuf, n);
    interp_lds_kernel<<<NBINS, ITHREADS, RN * sizeof(float), stream>>>(
        p4, grid, cursor, osort, cap);
    permute_kernel<<<blocks_pt, 256, 0, stream>>>(osort, posbuf, out, n);
}